// Round 16
// baseline (2559.561 us; speedup 1.0000x reference)
//
#include <hip/hip_runtime.h>
#include <hip/hip_bf16.h>

#define N_VOX 150000
#define CH 32
#define KVOL 27
#define NCLS 20
#define TOT (KVOL * N_VOX)          // 4,050,000
#define MPAD 150016                 // 586*256
#define NCB 293                     // coarse buckets (sv>>9), 512 rows each
#define NE1 8192                    // entries per scat block
#define NBLK1 495                   // ceil(TOT/8192)
#define WG_U32 (KVOL * 512)         // 13824 u32 per prepped weight set
#define KSTR 288                    // LDS u32 stride per k (8 rows): == 0 mod 32
#define JSTR 36                     // LDS u32 stride per cin-pair: == 4 mod 32

typedef _Float16 f16x2 __attribute__((ext_vector_type(2)));
union U32H { unsigned int u; f16x2 h; };

__device__ __forceinline__ unsigned int pk_f16(float a, float b) {
  auto r = __builtin_amdgcn_cvt_pkrtz(a, b);   // __fp16 ext_vector(2)
  unsigned int u;
  __builtin_memcpy(&u, &r, 4);
  return u;
}
__device__ __forceinline__ float f16_lo(unsigned int u) { U32H v; v.u = u; return (float)v.h[0]; }
__device__ __forceinline__ float f16_hi(unsigned int u) { U32H v; v.u = u; return (float)v.h[1]; }

#if __has_builtin(__builtin_amdgcn_fdot2)
#define DOT2(x, w, c) __builtin_amdgcn_fdot2((x), (w), (c), false)
#else
#define DOT2(x, w, c) fmaf((float)(x)[0], (float)(w)[0], fmaf((float)(x)[1], (float)(w)[1], (c)))
#endif

// ==================== build: 2-pass counting sort (unchanged) ===============
__global__ __launch_bounds__(512) void k_c0(const int* __restrict__ sa,
                                            const int* __restrict__ sb,
                                            int* __restrict__ ccnt) {
  __shared__ int h[512];
  const int t = threadIdx.x;
  const int z = blockIdx.z;
  const int* s_ = z ? sb : sa;
  const int e0 = blockIdx.x * NE1;
  h[t] = 0;
  __syncthreads();
#pragma unroll
  for (int i = 0; i < NE1 / 512; i++) {
    int e = e0 + t + i * 512;
    if (e < TOT) atomicAdd(&h[s_[e] >> 9], 1);
  }
  __syncthreads();
  if (h[t]) atomicAdd(&ccnt[z * 512 + t], h[t]);
}

__global__ __launch_bounds__(512) void k_cscan(const int* __restrict__ ccnt,
                                               int* __restrict__ cbase,
                                               int* __restrict__ ccur) {
  __shared__ int sc[512];
  const int t = threadIdx.x;
  const int z = blockIdx.x;
  int v = ccnt[z * 512 + t];
  sc[t] = v;
  __syncthreads();
  for (int s = 1; s < 512; s <<= 1) {
    int a = (t >= s) ? sc[t - s] : 0;
    __syncthreads();
    sc[t] += a;
    __syncthreads();
  }
  int excl = sc[t] - v;
  cbase[z * 512 + t] = excl;
  ccur[z * 512 + t] = excl;
}

__global__ __launch_bounds__(512) void k_scat(const int* __restrict__ s_,
                                              const int* __restrict__ g_,
                                              int* __restrict__ ccur,
                                              unsigned int* __restrict__ tmp,
                                              int z) {
  __shared__ int h[512], lb[512], lc[512];
  const int t = threadIdx.x;
  const int e0 = blockIdx.x * NE1;
  h[t] = 0;
  __syncthreads();
#pragma unroll
  for (int i = 0; i < NE1 / 512; i++) {
    int e = e0 + t + i * 512;
    if (e < TOT) atomicAdd(&h[s_[e] >> 9], 1);
  }
  __syncthreads();
  lb[t] = h[t] ? atomicAdd(&ccur[z * 512 + t], h[t]) : 0;
  lc[t] = 0;
  __syncthreads();
#pragma unroll
  for (int i = 0; i < NE1 / 512; i++) {
    int e = e0 + t + i * 512;
    if (e < TOT) {
      int sv = s_[e];
      int bk = sv >> 9;
      int k = e / N_VOX;
      unsigned int p = ((unsigned int)(sv & 511) << 23) |
                       ((unsigned int)g_[e] << 5) | (unsigned int)k;
      int pos = lb[bk] + atomicAdd(&lc[bk], 1);
      tmp[pos] = p;
    }
  }
}

__global__ __launch_bounds__(512) void k_p2(const unsigned int* __restrict__ tmp,
                                            const int* __restrict__ cbase,
                                            int* __restrict__ off2,
                                            unsigned int* __restrict__ pl,
                                            int z) {
  __shared__ int h[512], sc[512], lc[512];
  const int t = threadIdx.x;
  const int b = blockIdx.x;
  const int rb = cbase[z * 512 + b];
  const int re = cbase[z * 512 + b + 1];
  h[t] = 0;
  __syncthreads();
  for (int i = rb + t; i < re; i += 512) atomicAdd(&h[tmp[i] >> 23], 1);
  __syncthreads();
  sc[t] = h[t];
  __syncthreads();
  for (int s = 1; s < 512; s <<= 1) {
    int a = (t >= s) ? sc[t - s] : 0;
    __syncthreads();
    sc[t] += a;
    __syncthreads();
  }
  int excl = sc[t] - h[t];
  off2[z * MPAD + b * 512 + t] = rb + excl;
  lc[t] = excl;
  __syncthreads();
  for (int i = rb + t; i < re; i += 512) {
    unsigned int p = tmp[i];
    int bin = (int)(p >> 23);
    int pos = rb + atomicAdd(&lc[bin], 1);
    pl[pos] = p & 0x7FFFFFu;
  }
}

// ==================== weight prep: [k][cinpair jj][cout] f16 pairs ==========
__global__ __launch_bounds__(256) void k_wprep(const float* __restrict__ W,
                                               unsigned int* __restrict__ out) {
  int i = blockIdx.x * 256 + threadIdx.x;
  if (i >= WG_U32) return;
  int k = i >> 9, r = i & 511, jj = r >> 5, c = r & 31;
  const float* wk = W + k * 1024;
  out[i] = pk_f16(wk[(2 * jj) * 32 + c], wk[(2 * jj + 1) * 32 + c]);
}

// ==================== f32 -> f16 activation convert =========================
__global__ __launch_bounds__(256) void k_tof16(const float4* __restrict__ in4,
                                               uint4* __restrict__ out4) {
  int i = blockIdx.x * 256 + threadIdx.x;
  if (i >= (N_VOX * CH) / 8) return;
  float4 f0 = in4[i * 2], f1 = in4[i * 2 + 1];
  uint4 o;
  o.x = pk_f16(f0.x, f0.y); o.y = pk_f16(f0.z, f0.w);
  o.z = pk_f16(f1.x, f1.y); o.w = pk_f16(f1.z, f1.w);
  out4[i] = o;
}

// ==================== dot2 conv kernel (dual-pipe W, batched loads) =========
// Block 512 = 64 groups of 8 lanes. Group owns ONE output row (contiguous CSR
// entries). Lane j owns cin-pair rows {j, j+8}: row j from LDS (31 KB stage,
// uniform bank base), row j+8 from GLOBAL -- but loaded in the BATCHED load
// phase (named uint4 regs, alongside the X gather) so the compiler keeps all
// ~19 loads per entry in flight instead of serializing them (r14's failure).
// 2-entry unroll bounds VGPR (~120); __launch_bounds__(512,4) pins <=128.

#define ENT_LOAD(S, E) \
  unsigned int p##S = pl[(E)]; \
  unsigned int gi##S = p##S >> 5; \
  int kk##S = (int)(p##S & 31u); \
  unsigned int xa##S = srcU[gi##S * 16 + j]; \
  unsigned int xb##S = srcU[gi##S * 16 + 8 + j]; \
  const uint4* wp##S = (const uint4*)(Wg + kk##S * 512 + (j + 8) * 32); \
  uint4 W##S##0 = wp##S[0], W##S##1 = wp##S[1], W##S##2 = wp##S[2], W##S##3 = wp##S[3]; \
  uint4 W##S##4 = wp##S[4], W##S##5 = wp##S[5], W##S##6 = wp##S[6], W##S##7 = wp##S[7];

#define QSTEP(S, Q) { \
  uint4 wA_ = *(const uint4*)(wa##S + (Q) * 4); \
  U32H a0_, a1_, a2_, a3_, b0_, b1_, b2_, b3_; \
  a0_.u = wA_.x; a1_.u = wA_.y; a2_.u = wA_.z; a3_.u = wA_.w; \
  b0_.u = W##S##Q.x; b1_.u = W##S##Q.y; b2_.u = W##S##Q.z; b3_.u = W##S##Q.w; \
  acc[(Q) * 4 + 0] = DOT2(x01##S.h, a0_.h, acc[(Q) * 4 + 0]); \
  acc[(Q) * 4 + 1] = DOT2(x01##S.h, a1_.h, acc[(Q) * 4 + 1]); \
  acc[(Q) * 4 + 2] = DOT2(x01##S.h, a2_.h, acc[(Q) * 4 + 2]); \
  acc[(Q) * 4 + 3] = DOT2(x01##S.h, a3_.h, acc[(Q) * 4 + 3]); \
  acc[(Q) * 4 + 0] = DOT2(x23##S.h, b0_.h, acc[(Q) * 4 + 0]); \
  acc[(Q) * 4 + 1] = DOT2(x23##S.h, b1_.h, acc[(Q) * 4 + 1]); \
  acc[(Q) * 4 + 2] = DOT2(x23##S.h, b2_.h, acc[(Q) * 4 + 2]); \
  acc[(Q) * 4 + 3] = DOT2(x23##S.h, b3_.h, acc[(Q) * 4 + 3]); }

#define ENT_DOT(S) { \
  const unsigned int* wa##S = sW + kk##S * KSTR + j * JSTR; \
  U32H x01##S, x23##S; x01##S.u = xa##S; x23##S.u = xb##S; \
  QSTEP(S, 0) QSTEP(S, 1) QSTEP(S, 2) QSTEP(S, 3) \
  QSTEP(S, 4) QSTEP(S, 5) QSTEP(S, 6) QSTEP(S, 7) }

__global__ __launch_bounds__(512, 4) void k_conv(
    const unsigned int* __restrict__ srcU, unsigned int* __restrict__ dstU,
    const int* __restrict__ off, const unsigned int* __restrict__ pl,
    const unsigned int* __restrict__ Wg, const float* __restrict__ bias) {
  __shared__ unsigned int sW[KVOL * KSTR];   // 31104 B (cin-pair rows 0..7)
  __shared__ float sB[CH];

  const int tid = threadIdx.x;
  for (int i = tid; i < KVOL * 256; i += 512) {
    int k = i >> 8, r = i & 255;
    sW[k * KSTR + (r >> 5) * JSTR + (r & 31)] = Wg[k * 512 + (r >> 5) * 32 + (r & 31)];
  }
  if (tid < CH) sB[tid] = bias[tid];
  __syncthreads();

  const int g = tid >> 3, j = tid & 7;
  const int row = blockIdx.x * 64 + g;
  int beg = 0, ee = 0;
  if (row < N_VOX) { beg = off[row]; ee = off[row + 1]; }

  float acc[CH];
#pragma unroll
  for (int t = 0; t < CH; t++) acc[t] = 0.f;

  int e = beg;
  for (; e + 2 <= ee; e += 2) {
    ENT_LOAD(0, e)
    ENT_LOAD(1, e + 1)
    ENT_DOT(0)
    ENT_DOT(1)
  }
  if (e < ee) {
    ENT_LOAD(2, e)
    ENT_DOT(2)
  }

  // butterfly reduce across the 8 lanes of the group
#pragma unroll
  for (int m = 1; m <= 4; m <<= 1) {
#pragma unroll
    for (int t = 0; t < CH; t++) acc[t] += __shfl_xor(acc[t], m);
  }

  if (row < N_VOX) {
    unsigned int w0 = 0, w1 = 0;
#pragma unroll
    for (int t = 0; t < 16; t++) {
      float lo = fmaxf(acc[2 * t] + sB[2 * t], 0.f);
      float hi = fmaxf(acc[2 * t + 1] + sB[2 * t + 1], 0.f);
      unsigned int pk = pk_f16(lo, hi);
      if ((t >> 1) == j) { if (t & 1) w1 = pk; else w0 = pk; }
    }
    uint2 o = {w0, w1};
    *(uint2*)(dstU + row * 16 + j * 2) = o;
  }
}

// ==================== logits kernel (f16 inputs) ============================
__global__ __launch_bounds__(256) void k_logits(
    const uint4* __restrict__ A4, const uint4* __restrict__ B4,
    const float* __restrict__ Wl, const float* __restrict__ bl,
    float* __restrict__ out) {
  __shared__ float sWl[CH * NCLS];
  __shared__ float sbl[NCLS];
  int tid = threadIdx.x;
  if (tid < CH * NCLS / 4) ((float4*)sWl)[tid] = ((const float4*)Wl)[tid];
  if (tid < NCLS) sbl[tid] = bl[tid];
  __syncthreads();
  int row = blockIdx.x * 256 + tid;
  if (row >= N_VOX) return;
  float acc[NCLS];
#pragma unroll
  for (int jj = 0; jj < NCLS; jj++) acc[jj] = sbl[jj];
#pragma unroll
  for (int q = 0; q < 4; q++) {
    uint4 a = A4[row * 4 + q], b = B4[row * 4 + q];
    unsigned int au[4] = {a.x, a.y, a.z, a.w}, bu[4] = {b.x, b.y, b.z, b.w};
#pragma unroll
    for (int t = 0; t < 4; t++) {
      int c = (q << 3) + (t << 1);
      float x0 = f16_lo(au[t]) + f16_lo(bu[t]);
      float x1 = f16_hi(au[t]) + f16_hi(bu[t]);
#pragma unroll
      for (int jj = 0; jj < NCLS; jj++) {
        acc[jj] = fmaf(x0, sWl[c * NCLS + jj], acc[jj]);
        acc[jj] = fmaf(x1, sWl[(c + 1) * NCLS + jj], acc[jj]);
      }
    }
  }
  float4* op = (float4*)(out + row * NCLS);
#pragma unroll
  for (int j5 = 0; j5 < NCLS / 4; j5++) {
    float4 v = {acc[j5 * 4], acc[j5 * 4 + 1], acc[j5 * 4 + 2], acc[j5 * 4 + 3]};
    op[j5] = v;
  }
}

// ==================== launch ================================================
extern "C" void kernel_launch(void* const* d_in, const int* in_sizes, int n_in,
                              void* d_out, int out_size, void* d_ws, size_t ws_size,
                              hipStream_t stream) {
  const float* in_feats = (const float*)d_in[0];
  const int*   ga       = (const int*)d_in[1];
  const int*   sa       = (const int*)d_in[2];
  const int*   gb       = (const int*)d_in[3];
  const int*   sb       = (const int*)d_in[4];
  const float* w1       = (const float*)d_in[5];
  const float* b1       = (const float*)d_in[6];
  const float* w1_2     = (const float*)d_in[7];
  const float* b1_2     = (const float*)d_in[8];
  const float* w2       = (const float*)d_in[9];
  const float* b2       = (const float*)d_in[10];
  const float* w3       = (const float*)d_in[11];
  const float* b3       = (const float*)d_in[12];
  const float* wl       = (const float*)d_in[13];
  const float* bl       = (const float*)d_in[14];
  float* out = (float*)d_out;

  // ---- workspace carve-up (u32 units, ~88.4 MB) ----
  unsigned int* wsu = (unsigned int*)d_ws;
  size_t o = 0;
  unsigned int* bufA = wsu + o; o += (size_t)MPAD * 16;
  unsigned int* bufB = wsu + o; o += (size_t)MPAD * 16;
  unsigned int* bufC = wsu + o; o += (size_t)MPAD * 16;
  unsigned int* inbf = wsu + o; o += (size_t)MPAD * 16;
  unsigned int* Wg1   = wsu + o; o += WG_U32;
  unsigned int* Wg1_2 = wsu + o; o += WG_U32;
  unsigned int* Wg2   = wsu + o; o += WG_U32;
  unsigned int* Wg3   = wsu + o; o += WG_U32;
  int* off2  = (int*)(wsu + o); o += 2 * MPAD;
  int* ccnt  = (int*)(wsu + o); o += 1024;
  int* cbase = (int*)(wsu + o); o += 1024;
  int* ccur  = (int*)(wsu + o); o += 1024;
  unsigned int* tmp = wsu + o; o += TOT;
  unsigned int* plA = wsu + o; o += TOT;
  unsigned int* plB = wsu + o; o += TOT;

  dim3 blk(256);
  const int g_conv = MPAD / 64;              // 2344 blocks x 512 thr
  const int g_wp   = (WG_U32 + 255) / 256;   // 54
  const int g_bf   = 2344;
  const int g_lg   = (N_VOX + 255) / 256;

  // ---- build row-keyed CSRs via 2-pass counting sort ----
  (void)hipMemsetAsync(ccnt, 0, 1024 * sizeof(int), stream);
  k_c0<<<dim3(NBLK1, 1, 2), dim3(512), 0, stream>>>(sa, sb, ccnt);
  k_cscan<<<2, dim3(512), 0, stream>>>(ccnt, cbase, ccur);
  k_scat<<<NBLK1, dim3(512), 0, stream>>>(sa, ga, ccur, tmp, 0);
  k_p2<<<NCB, dim3(512), 0, stream>>>(tmp, cbase, off2, plA, 0);
  k_scat<<<NBLK1, dim3(512), 0, stream>>>(sb, gb, ccur, tmp, 1);
  k_p2<<<NCB, dim3(512), 0, stream>>>(tmp, cbase, off2, plB, 1);

  // ---- weight prep + activation convert ----
  k_wprep<<<g_wp, blk, 0, stream>>>(w1,   Wg1);
  k_wprep<<<g_wp, blk, 0, stream>>>(w1_2, Wg1_2);
  k_wprep<<<g_wp, blk, 0, stream>>>(w2,   Wg2);
  k_wprep<<<g_wp, blk, 0, stream>>>(w3,   Wg3);
  k_tof16<<<g_bf, blk, 0, stream>>>((const float4*)in_feats, (uint4*)inbf);

  // ---- 4 conv layers (row-parallel, no atomics) ----
  const int* offA = off2;
  const int* offB = off2 + MPAD;
  k_conv<<<g_conv, dim3(512), 0, stream>>>(inbf, bufA, offA, plA, Wg1, b1);
  k_conv<<<g_conv, dim3(512), 0, stream>>>(bufA, bufB, offB, plB, Wg1_2, b1_2);
  k_conv<<<g_conv, dim3(512), 0, stream>>>(inbf, bufC, offB, plB, Wg2, b2);
  k_conv<<<g_conv, dim3(512), 0, stream>>>(bufC, bufA, offA, plA, Wg3, b3);

  // ---- logits ----
  k_logits<<<g_lg, blk, 0, stream>>>((const uint4*)bufB, (const uint4*)bufA,
                                     wl, bl, out);
}

// Round 17
// 925.710 us; speedup vs baseline: 2.7650x; 2.7650x over previous
//
#include <hip/hip_runtime.h>
#include <hip/hip_bf16.h>

#define N_VOX 150000
#define CH 32
#define KVOL 27
#define NCLS 20
#define TOT (KVOL * N_VOX)          // 4,050,000
#define MPAD 150016                 // 586*256
#define NCB 293                     // coarse buckets (sv>>9), 512 rows each
#define NE1 8192                    // entries per scat block
#define NBLK1 495                   // ceil(TOT/8192)
#define WG_U32 (KVOL * 512)         // 13824 u32 per prepped weight set
#define KSTR 576                    // LDS u32 stride per k: >=16*JSTR AND == 0 mod 32
#define JSTR 36                     // LDS u32 stride per cin-pair: == 4 mod 32

typedef _Float16 f16x2 __attribute__((ext_vector_type(2)));
union U32H { unsigned int u; f16x2 h; };

__device__ __forceinline__ unsigned int pk_f16(float a, float b) {
  auto r = __builtin_amdgcn_cvt_pkrtz(a, b);   // __fp16 ext_vector(2)
  unsigned int u;
  __builtin_memcpy(&u, &r, 4);
  return u;
}
__device__ __forceinline__ float f16_lo(unsigned int u) { U32H v; v.u = u; return (float)v.h[0]; }
__device__ __forceinline__ float f16_hi(unsigned int u) { U32H v; v.u = u; return (float)v.h[1]; }

#if __has_builtin(__builtin_amdgcn_fdot2)
#define DOT2(x, w, c) __builtin_amdgcn_fdot2((x), (w), (c), false)
#else
#define DOT2(x, w, c) fmaf((float)(x)[0], (float)(w)[0], fmaf((float)(x)[1], (float)(w)[1], (c)))
#endif

// ==================== build: 2-pass counting sort ===========================
__global__ __launch_bounds__(512) void k_c0(const int* __restrict__ sa,
                                            const int* __restrict__ sb,
                                            int* __restrict__ ccnt) {
  __shared__ int h[512];
  const int t = threadIdx.x;
  const int z = blockIdx.z;
  const int* s_ = z ? sb : sa;
  const int e0 = blockIdx.x * NE1;
  h[t] = 0;
  __syncthreads();
#pragma unroll
  for (int i = 0; i < NE1 / 512; i++) {
    int e = e0 + t + i * 512;
    if (e < TOT) atomicAdd(&h[s_[e] >> 9], 1);
  }
  __syncthreads();
  if (h[t]) atomicAdd(&ccnt[z * 512 + t], h[t]);
}

__global__ __launch_bounds__(512) void k_cscan(const int* __restrict__ ccnt,
                                               int* __restrict__ cbase,
                                               int* __restrict__ ccur) {
  __shared__ int sc[512];
  const int t = threadIdx.x;
  const int z = blockIdx.x;
  int v = ccnt[z * 512 + t];
  sc[t] = v;
  __syncthreads();
  for (int s = 1; s < 512; s <<= 1) {
    int a = (t >= s) ? sc[t - s] : 0;
    __syncthreads();
    sc[t] += a;
    __syncthreads();
  }
  int excl = sc[t] - v;
  cbase[z * 512 + t] = excl;
  ccur[z * 512 + t] = excl;
}

__global__ __launch_bounds__(512) void k_scat(const int* __restrict__ s_,
                                              const int* __restrict__ g_,
                                              int* __restrict__ ccur,
                                              unsigned int* __restrict__ tmp,
                                              int z) {
  __shared__ int h[512], lb[512], lc[512];
  const int t = threadIdx.x;
  const int e0 = blockIdx.x * NE1;
  h[t] = 0;
  __syncthreads();
#pragma unroll
  for (int i = 0; i < NE1 / 512; i++) {
    int e = e0 + t + i * 512;
    if (e < TOT) atomicAdd(&h[s_[e] >> 9], 1);
  }
  __syncthreads();
  lb[t] = h[t] ? atomicAdd(&ccur[z * 512 + t], h[t]) : 0;
  lc[t] = 0;
  __syncthreads();
#pragma unroll
  for (int i = 0; i < NE1 / 512; i++) {
    int e = e0 + t + i * 512;
    if (e < TOT) {
      int sv = s_[e];
      int bk = sv >> 9;
      int k = e / N_VOX;
      unsigned int p = ((unsigned int)(sv & 511) << 23) |
                       ((unsigned int)g_[e] << 5) | (unsigned int)k;
      int pos = lb[bk] + atomicAdd(&lc[bk], 1);
      tmp[pos] = p;
    }
  }
}

__global__ __launch_bounds__(512) void k_p2(const unsigned int* __restrict__ tmp,
                                            const int* __restrict__ cbase,
                                            int* __restrict__ off2,
                                            unsigned int* __restrict__ pl,
                                            int z) {
  __shared__ int h[512], sc[512], lc[512];
  const int t = threadIdx.x;
  const int b = blockIdx.x;
  const int rb = cbase[z * 512 + b];
  const int re = cbase[z * 512 + b + 1];
  h[t] = 0;
  __syncthreads();
  for (int i = rb + t; i < re; i += 512) atomicAdd(&h[tmp[i] >> 23], 1);
  __syncthreads();
  sc[t] = h[t];
  __syncthreads();
  for (int s = 1; s < 512; s <<= 1) {
    int a = (t >= s) ? sc[t - s] : 0;
    __syncthreads();
    sc[t] += a;
    __syncthreads();
  }
  int excl = sc[t] - h[t];
  off2[z * MPAD + b * 512 + t] = rb + excl;
  lc[t] = excl;
  __syncthreads();
  for (int i = rb + t; i < re; i += 512) {
    unsigned int p = tmp[i];
    int bin = (int)(p >> 23);
    int pos = rb + atomicAdd(&lc[bin], 1);
    pl[pos] = p & 0x7FFFFFu;
  }
}

// ==================== weight prep: [k][cinpair jj][cout] f16 pairs ==========
__global__ __launch_bounds__(256) void k_wprep(const float* __restrict__ W,
                                               unsigned int* __restrict__ out) {
  int i = blockIdx.x * 256 + threadIdx.x;
  if (i >= WG_U32) return;
  int k = i >> 9, r = i & 511, jj = r >> 5, c = r & 31;
  const float* wk = W + k * 1024;
  out[i] = pk_f16(wk[(2 * jj) * 32 + c], wk[(2 * jj + 1) * 32 + c]);
}

// ==================== f32 -> f16 activation convert =========================
__global__ __launch_bounds__(256) void k_tof16(const float4* __restrict__ in4,
                                               uint4* __restrict__ out4) {
  int i = blockIdx.x * 256 + threadIdx.x;
  if (i >= (N_VOX * CH) / 8) return;
  float4 f0 = in4[i * 2], f1 = in4[i * 2 + 1];
  uint4 o;
  o.x = pk_f16(f0.x, f0.y); o.y = pk_f16(f0.z, f0.w);
  o.z = pk_f16(f1.x, f1.y); o.w = pk_f16(f1.z, f1.w);
  out4[i] = o;
}

// ==================== dot2 conv kernel (round-13 best) ======================
// Block 512 = 64 groups of 8 lanes. Group owns ONE output row (contiguous CSR
// entries). Lane j owns cin-pair rows {j, j+8}, all W from LDS. KSTR=576:
// >=16*JSTR (no overlap) and == 0 mod 32 (uniform bank base); JSTR=36: the 8
// lanes cover all 32 banks per b128 phase. 4-entry unroll = 12 batched loads.
// LDS data-path is saturated (~16 cyc/b128 x 31.6K instr/CU ~= duration):
// this is the structural floor of the vector-dot formulation.

#define ENT_LOAD(S, E) \
  unsigned int p##S = pl[(E)]; \
  unsigned int gi##S = p##S >> 5; \
  int kk##S = (int)(p##S & 31u); \
  unsigned int xa##S = srcU[gi##S * 16 + j]; \
  unsigned int xb##S = srcU[gi##S * 16 + 8 + j];

#define ENT_DOT(S) { \
  const unsigned int* wb_ = sW + kk##S * KSTR + j * JSTR; \
  U32H x01_, x23_; x01_.u = xa##S; x23_.u = xb##S; \
  _Pragma("unroll") for (int q = 0; q < 8; q++) { \
    uint4 wA_ = *(const uint4*)(wb_ + q * 4); \
    uint4 wB_ = *(const uint4*)(wb_ + 8 * JSTR + q * 4); \
    U32H a0_, a1_, a2_, a3_, b0_, b1_, b2_, b3_; \
    a0_.u = wA_.x; a1_.u = wA_.y; a2_.u = wA_.z; a3_.u = wA_.w; \
    b0_.u = wB_.x; b1_.u = wB_.y; b2_.u = wB_.z; b3_.u = wB_.w; \
    acc[q * 4 + 0] = DOT2(x01_.h, a0_.h, acc[q * 4 + 0]); \
    acc[q * 4 + 1] = DOT2(x01_.h, a1_.h, acc[q * 4 + 1]); \
    acc[q * 4 + 2] = DOT2(x01_.h, a2_.h, acc[q * 4 + 2]); \
    acc[q * 4 + 3] = DOT2(x01_.h, a3_.h, acc[q * 4 + 3]); \
    acc[q * 4 + 0] = DOT2(x23_.h, b0_.h, acc[q * 4 + 0]); \
    acc[q * 4 + 1] = DOT2(x23_.h, b1_.h, acc[q * 4 + 1]); \
    acc[q * 4 + 2] = DOT2(x23_.h, b2_.h, acc[q * 4 + 2]); \
    acc[q * 4 + 3] = DOT2(x23_.h, b3_.h, acc[q * 4 + 3]); \
  } }

__global__ __launch_bounds__(512, 2) void k_conv(
    const unsigned int* __restrict__ srcU, unsigned int* __restrict__ dstU,
    const int* __restrict__ off, const unsigned int* __restrict__ pl,
    const unsigned int* __restrict__ Wg, const float* __restrict__ bias) {
  __shared__ unsigned int sW[KVOL * KSTR];   // 62208 B
  __shared__ float sB[CH];

  const int tid = threadIdx.x;
  for (int i = tid; i < KVOL * 512; i += 512) {
    int k = i >> 9, r = i & 511;
    sW[k * KSTR + (r >> 5) * JSTR + (r & 31)] = Wg[i];
  }
  if (tid < CH) sB[tid] = bias[tid];
  __syncthreads();

  const int g = tid >> 3, j = tid & 7;
  const int row = blockIdx.x * 64 + g;
  int beg = 0, ee = 0;
  if (row < N_VOX) { beg = off[row]; ee = off[row + 1]; }

  float acc[CH];
#pragma unroll
  for (int t = 0; t < CH; t++) acc[t] = 0.f;

  int e = beg;
  for (; e + 4 <= ee; e += 4) {
    ENT_LOAD(0, e)
    ENT_LOAD(1, e + 1)
    ENT_LOAD(4, e + 2)
    ENT_LOAD(5, e + 3)
    ENT_DOT(0)
    ENT_DOT(1)
    ENT_DOT(4)
    ENT_DOT(5)
  }
  for (; e + 2 <= ee; e += 2) {
    ENT_LOAD(2, e)
    ENT_LOAD(3, e + 1)
    ENT_DOT(2)
    ENT_DOT(3)
  }
  if (e < ee) {
    ENT_LOAD(6, e)
    ENT_DOT(6)
  }

  // butterfly reduce across the 8 lanes of the group
#pragma unroll
  for (int m = 1; m <= 4; m <<= 1) {
#pragma unroll
    for (int t = 0; t < CH; t++) acc[t] += __shfl_xor(acc[t], m);
  }

  if (row < N_VOX) {
    unsigned int w0 = 0, w1 = 0;
#pragma unroll
    for (int t = 0; t < 16; t++) {
      float lo = fmaxf(acc[2 * t] + sB[2 * t], 0.f);
      float hi = fmaxf(acc[2 * t + 1] + sB[2 * t + 1], 0.f);
      unsigned int pk = pk_f16(lo, hi);
      if ((t >> 1) == j) { if (t & 1) w1 = pk; else w0 = pk; }
    }
    uint2 o = {w0, w1};
    *(uint2*)(dstU + row * 16 + j * 2) = o;
  }
}

// ==================== logits kernel (f16 inputs) ============================
__global__ __launch_bounds__(256) void k_logits(
    const uint4* __restrict__ A4, const uint4* __restrict__ B4,
    const float* __restrict__ Wl, const float* __restrict__ bl,
    float* __restrict__ out) {
  __shared__ float sWl[CH * NCLS];
  __shared__ float sbl[NCLS];
  int tid = threadIdx.x;
  if (tid < CH * NCLS / 4) ((float4*)sWl)[tid] = ((const float4*)Wl)[tid];
  if (tid < NCLS) sbl[tid] = bl[tid];
  __syncthreads();
  int row = blockIdx.x * 256 + tid;
  if (row >= N_VOX) return;
  float acc[NCLS];
#pragma unroll
  for (int jj = 0; jj < NCLS; jj++) acc[jj] = sbl[jj];
#pragma unroll
  for (int q = 0; q < 4; q++) {
    uint4 a = A4[row * 4 + q], b = B4[row * 4 + q];
    unsigned int au[4] = {a.x, a.y, a.z, a.w}, bu[4] = {b.x, b.y, b.z, b.w};
#pragma unroll
    for (int t = 0; t < 4; t++) {
      int c = (q << 3) + (t << 1);
      float x0 = f16_lo(au[t]) + f16_lo(bu[t]);
      float x1 = f16_hi(au[t]) + f16_hi(bu[t]);
#pragma unroll
      for (int jj = 0; jj < NCLS; jj++) {
        acc[jj] = fmaf(x0, sWl[c * NCLS + jj], acc[jj]);
        acc[jj] = fmaf(x1, sWl[(c + 1) * NCLS + jj], acc[jj]);
      }
    }
  }
  float4* op = (float4*)(out + row * NCLS);
#pragma unroll
  for (int j5 = 0; j5 < NCLS / 4; j5++) {
    float4 v = {acc[j5 * 4], acc[j5 * 4 + 1], acc[j5 * 4 + 2], acc[j5 * 4 + 3]};
    op[j5] = v;
  }
}

// ==================== launch ================================================
extern "C" void kernel_launch(void* const* d_in, const int* in_sizes, int n_in,
                              void* d_out, int out_size, void* d_ws, size_t ws_size,
                              hipStream_t stream) {
  const float* in_feats = (const float*)d_in[0];
  const int*   ga       = (const int*)d_in[1];
  const int*   sa       = (const int*)d_in[2];
  const int*   gb       = (const int*)d_in[3];
  const int*   sb       = (const int*)d_in[4];
  const float* w1       = (const float*)d_in[5];
  const float* b1       = (const float*)d_in[6];
  const float* w1_2     = (const float*)d_in[7];
  const float* b1_2     = (const float*)d_in[8];
  const float* w2       = (const float*)d_in[9];
  const float* b2       = (const float*)d_in[10];
  const float* w3       = (const float*)d_in[11];
  const float* b3       = (const float*)d_in[12];
  const float* wl       = (const float*)d_in[13];
  const float* bl       = (const float*)d_in[14];
  float* out = (float*)d_out;

  // ---- workspace carve-up (u32 units, ~88.4 MB) ----
  unsigned int* wsu = (unsigned int*)d_ws;
  size_t o = 0;
  unsigned int* bufA = wsu + o; o += (size_t)MPAD * 16;
  unsigned int* bufB = wsu + o; o += (size_t)MPAD * 16;
  unsigned int* bufC = wsu + o; o += (size_t)MPAD * 16;
  unsigned int* inbf = wsu + o; o += (size_t)MPAD * 16;
  unsigned int* Wg1   = wsu + o; o += WG_U32;
  unsigned int* Wg1_2 = wsu + o; o += WG_U32;
  unsigned int* Wg2   = wsu + o; o += WG_U32;
  unsigned int* Wg3   = wsu + o; o += WG_U32;
  int* off2  = (int*)(wsu + o); o += 2 * MPAD;
  int* ccnt  = (int*)(wsu + o); o += 1024;
  int* cbase = (int*)(wsu + o); o += 1024;
  int* ccur  = (int*)(wsu + o); o += 1024;
  unsigned int* tmp = wsu + o; o += TOT;
  unsigned int* plA = wsu + o; o += TOT;
  unsigned int* plB = wsu + o; o += TOT;

  dim3 blk(256);
  const int g_conv = MPAD / 64;              // 2344 blocks x 512 thr
  const int g_wp   = (WG_U32 + 255) / 256;   // 54
  const int g_bf   = 2344;
  const int g_lg   = (N_VOX + 255) / 256;

  // ---- build row-keyed CSRs via 2-pass counting sort ----
  (void)hipMemsetAsync(ccnt, 0, 1024 * sizeof(int), stream);
  k_c0<<<dim3(NBLK1, 1, 2), dim3(512), 0, stream>>>(sa, sb, ccnt);
  k_cscan<<<2, dim3(512), 0, stream>>>(ccnt, cbase, ccur);
  k_scat<<<NBLK1, dim3(512), 0, stream>>>(sa, ga, ccur, tmp, 0);
  k_p2<<<NCB, dim3(512), 0, stream>>>(tmp, cbase, off2, plA, 0);
  k_scat<<<NBLK1, dim3(512), 0, stream>>>(sb, gb, ccur, tmp, 1);
  k_p2<<<NCB, dim3(512), 0, stream>>>(tmp, cbase, off2, plB, 1);

  // ---- weight prep + activation convert ----
  k_wprep<<<g_wp, blk, 0, stream>>>(w1,   Wg1);
  k_wprep<<<g_wp, blk, 0, stream>>>(w1_2, Wg1_2);
  k_wprep<<<g_wp, blk, 0, stream>>>(w2,   Wg2);
  k_wprep<<<g_wp, blk, 0, stream>>>(w3,   Wg3);
  k_tof16<<<g_bf, blk, 0, stream>>>((const float4*)in_feats, (uint4*)inbf);

  // ---- 4 conv layers (row-parallel, no atomics) ----
  const int* offA = off2;
  const int* offB = off2 + MPAD;
  k_conv<<<g_conv, dim3(512), 0, stream>>>(inbf, bufA, offA, plA, Wg1, b1);
  k_conv<<<g_conv, dim3(512), 0, stream>>>(bufA, bufB, offB, plB, Wg1_2, b1_2);
  k_conv<<<g_conv, dim3(512), 0, stream>>>(inbf, bufC, offB, plB, Wg2, b2);
  k_conv<<<g_conv, dim3(512), 0, stream>>>(bufC, bufA, offA, plA, Wg3, b3);

  // ---- logits ----
  k_logits<<<g_lg, blk, 0, stream>>>((const uint4*)bufB, (const uint4*)bufA,
                                     wl, bl, out);
}